// Round 1
// baseline (56.267 us; speedup 1.0000x reference)
//
#include <hip/hip_runtime.h>

// mi = BETA * sum_d ( E[y_d^2] - (E[y_d])^2 )  over y: [1024, 256] fp32.
// Derivation: mean_i mean_j (y_jd - y_id)^2 = 2*Var_d; the /2 cancels.

#define N_ROWS 1024
#define D 256
#define NBLK 64
#define ROWS_PER_BLK (N_ROWS / NBLK)   // 16
#define BETA 0.001f

// Kernel 1: block b handles rows [b*16, b*16+16); thread t = dim t.
// Coalesced: in each row pass, the 256 threads read one contiguous 1KB row.
// Partials: ws[b*512 + d] = sum, ws[b*512 + 256 + d] = sumsq.  (128 KB total)
__global__ void club_partial(const float* __restrict__ y, float* __restrict__ ws) {
    const int d = threadIdx.x;                 // 0..255
    const int b = blockIdx.x;                  // 0..63
    const float* p = y + (size_t)b * ROWS_PER_BLK * D + d;
    float s = 0.f, s2 = 0.f;
#pragma unroll
    for (int r = 0; r < ROWS_PER_BLK; ++r) {
        float v = p[r * D];
        s  += v;
        s2 += v * v;
    }
    ws[b * (2 * D) + d]     = s;
    ws[b * (2 * D) + D + d] = s2;
}

// Kernel 2: one block, 256 threads. Thread d folds the 64 block-partials,
// forms the per-dim variance, then block-reduces to the scalar.
__global__ void club_final(const float* __restrict__ ws, float* __restrict__ out) {
    const int d = threadIdx.x;
    float s = 0.f, s2 = 0.f;
#pragma unroll 8
    for (int g = 0; g < NBLK; ++g) {
        s  += ws[g * (2 * D) + d];
        s2 += ws[g * (2 * D) + D + d];
    }
    const float invN = 1.0f / (float)N_ROWS;
    float mu = s * invN;
    float v  = s2 * invN - mu * mu;   // per-dim variance contribution

    // wave(64)-level shuffle reduction
#pragma unroll
    for (int off = 32; off > 0; off >>= 1)
        v += __shfl_down(v, off, 64);

    __shared__ float lds[4];
    const int wave = threadIdx.x >> 6;
    const int lane = threadIdx.x & 63;
    if (lane == 0) lds[wave] = v;
    __syncthreads();
    if (threadIdx.x == 0) {
        float t = lds[0] + lds[1] + lds[2] + lds[3];
        out[0] = t * BETA;
    }
}

extern "C" void kernel_launch(void* const* d_in, const int* in_sizes, int n_in,
                              void* d_out, int out_size, void* d_ws, size_t ws_size,
                              hipStream_t stream) {
    const float* y = (const float*)d_in[0];
    float* ws = (float*)d_ws;          // needs NBLK*2*D*4 = 128 KB
    float* out = (float*)d_out;

    club_partial<<<NBLK, D, 0, stream>>>(y, ws);
    club_final<<<1, D, 0, stream>>>(ws, out);
}